// Round 2
// baseline (891.336 us; speedup 1.0000x reference)
//
#include <hip/hip_runtime.h>

#define BN   8
#define TMAX 256
#define UMAX 128
#define U1   129   // U_MAX + 1
#define VV   512
#define SD   392   // padded diagonal count (max s used = 383, prefetch reads to 386)
#define PS   132   // padded row stride (even -> aligned float2 at even u)
#define NEG  -1e30f
#define PF   4     // prefetch ring depth

__device__ __forceinline__ float logaddexpf_(float a, float b) {
    float mx = fmaxf(a, b);
    float d  = fabsf(a - b);
    return mx + __logf(1.0f + __expf(-d));   // inputs finite or ~-1e30; exact enough vs thr=31
}

// One wave per (b,t,u) row of 512 logits: LSE + extract blank/emit logp.
// Writes DIAGONAL-major scratch: bD[b][s=t+u][u] = blank_logp(t,u),
// eD[b][s=t+u][u+1] = emit_logp(t,u)  (shifted so consumer reads are aligned).
__global__ __launch_bounds__(256) void lse_extract(
        const float* __restrict__ logits,
        const int*   __restrict__ y,
        const int*   __restrict__ Tl,
        const int*   __restrict__ Ul,
        float* __restrict__ blankD,
        float* __restrict__ emitD) {
    int lane = threadIdx.x & 63;
    int row  = blockIdx.x * 4 + (threadIdx.x >> 6);
    if (row >= BN * TMAX * U1) return;
    int b   = row / (TMAX * U1);
    int rem = row - b * (TMAX * U1);
    int t   = rem / U1;
    int u   = rem - t * U1;
    if (t >= Tl[b] || u > Ul[b]) return;     // never feeds the DP

    const float4* base = (const float4*)(logits + (size_t)row * VV);
    float4 r0 = base[lane * 2];
    float4 r1 = base[lane * 2 + 1];

    float m = fmaxf(fmaxf(fmaxf(r0.x, r0.y), fmaxf(r0.z, r0.w)),
                    fmaxf(fmaxf(r1.x, r1.y), fmaxf(r1.z, r1.w)));
#pragma unroll
    for (int off = 32; off > 0; off >>= 1) m = fmaxf(m, __shfl_xor(m, off));

    float s = __expf(r0.x - m) + __expf(r0.y - m) + __expf(r0.z - m) + __expf(r0.w - m)
            + __expf(r1.x - m) + __expf(r1.y - m) + __expf(r1.z - m) + __expf(r1.w - m);
#pragma unroll
    for (int off = 32; off > 0; off >>= 1) s += __shfl_xor(s, off);

    float lse = m + __logf(s);
    int sd = t + u;
    if (lane == 0)
        blankD[((size_t)b * SD + sd) * PS + u] = r0.x - lse;
    if (u < UMAX) {
        int yv = y[b * UMAX + u];            // wave-uniform
        if ((yv >> 3) == lane) {
            int e = yv & 7;
            float v = (e == 0) ? r0.x : (e == 1) ? r0.y : (e == 2) ? r0.z : (e == 3) ? r0.w
                    : (e == 4) ? r1.x : (e == 5) ? r1.y : (e == 6) ? r1.z : r1.w;
            emitD[((size_t)b * SD + sd) * PS + (u + 1)] = v - lse;
        }
    }
}

// Barrier-free wavefront DP: one WAVE per batch element (8 waves, 1 block).
// Lane L owns columns u=2L, 2L+1; lane 63 additionally owns u=128.
// alpha[t,u] = LAE(alpha[t-1,u]+blank[t-1,u], alpha[t,u-1]+emit[t,u-1]).
// Cross-lane dep: one __shfl_up per diagonal. Depth-4 register prefetch ring
// hides L2 latency (no __syncthreads -> no vmcnt(0) barrier drain).
__global__ __launch_bounds__(512) void dp_fused(
        const float* __restrict__ blankD,
        const float* __restrict__ emitD,
        const int*   __restrict__ Tlp,
        const int*   __restrict__ Ulp,
        float* __restrict__ out) {
    __shared__ float part[BN];
    int w = threadIdx.x >> 6;                 // batch index (one wave each)
    int L = threadIdx.x & 63;
    int Tl = Tlp[w], Ul = Ulp[w];
    int dend = Tl - 1 + Ul;                   // >= 191 for this problem
    const float* bD = blankD + (size_t)w * SD * PS;
    const float* eD = emitD  + (size_t)w * SD * PS;

    int  u0 = 2 * L, u1 = 2 * L + 1;
    bool lx = (L == 63);                      // owns u=128 extra slot

    // previous-diagonal alpha values for owned columns
    float p0 = (L == 0) ? 0.0f : NEG;         // alpha[0,0] = 0 on diagonal 0
    float p1 = NEG, px = NEG;

    // prefetch rings: slot r holds source diagonal s with (s & 3) == r
    float rb0[PF], rb1[PF], re0[PF], re1[PF], rbx[PF], rex[PF];
#pragma unroll
    for (int i = 0; i < PF; ++i) {
        float2 fb = *(const float2*)(bD + i * PS + u0);
        float2 fe = *(const float2*)(eD + i * PS + u0);
        rb0[i] = fb.x; rb1[i] = fb.y; re0[i] = fe.x; re1[i] = fe.y;
        rbx[i] = lx ? bD[i * PS + 128] : NEG;
        rex[i] = lx ? eD[i * PS + 128] : NEG;
    }

    for (int d = 1; d <= dend; ++d) {
        int r = (d - 1) & (PF - 1);           // ring slot holding s = d-1
        float b0 = rb0[r], b1 = rb1[r], e0 = re0[r], e1 = re1[r];
        float bx = rbx[r], ex = rex[r];

        float pm1 = __shfl_up(p1, 1);         // alpha[prev diag][u0-1] from lane L-1
        if (L == 0) pm1 = NEG;

        int ulo = d - (Tl - 1); if (ulo < 0) ulo = 0;
        int uhi = (d < Ul) ? d : Ul;

        // u==0 edge (no emit) and u==d edge (no blank) fall out automatically:
        // the missing parent is NEG and logaddexp(NEG, x) == x.
        float c0 = logaddexpf_(p0 + b0, pm1 + e0);
        float c1 = logaddexpf_(p1 + b1, p0  + e1);
        float cx = logaddexpf_(px + bx, p1  + ex);

        p0 = (u0 >= ulo && u0 <= uhi) ? c0 : NEG;
        p1 = (u1 >= ulo && u1 <= uhi) ? c1 : NEG;
        px = (lx && 128 >= ulo && 128 <= uhi) ? cx : NEG;

        // refill ring slot with source diagonal s = d-1+PF (consumed at d+PF)
        int s = d - 1 + PF;                   // <= dend-1+PF <= 386 < SD
        float2 fb = *(const float2*)(bD + s * PS + u0);
        float2 fe = *(const float2*)(eD + s * PS + u0);
        rb0[r] = fb.x; rb1[r] = fb.y; re0[r] = fe.x; re1[r] = fe.y;
        if (lx) { rbx[r] = bD[s * PS + 128]; rex[r] = eD[s * PS + 128]; }
    }

    // alpha[Tl-1, Ul] lives in the owner lane's register
    bool own;
    float afin;
    if (Ul == 128) { own = lx; afin = px; }
    else           { own = (L == (Ul >> 1)); afin = (Ul & 1) ? p1 : p0; }
    if (own) {
        float lp = afin + bD[(size_t)dend * PS + Ul];   // + blank[Tl-1, Ul]
        part[w] = lp;
    }
    __syncthreads();
    if (threadIdx.x == 0) {
        float acc = 0.0f;
#pragma unroll
        for (int i = 0; i < BN; ++i) acc += part[i];
        *out = -acc * (1.0f / BN);
    }
}

extern "C" void kernel_launch(void* const* d_in, const int* in_sizes, int n_in,
                              void* d_out, int out_size, void* d_ws, size_t ws_size,
                              hipStream_t stream) {
    const float* logits = (const float*)d_in[0];
    const int*   y      = (const int*)d_in[1];
    const int*   Tl     = (const int*)d_in[2];
    const int*   Ul     = (const int*)d_in[3];
    float* out = (float*)d_out;

    float* blankD = (float*)d_ws;                       // 8*392*132 floats
    float* emitD  = blankD + (size_t)BN * SD * PS;      // 8*392*132 floats

    int rows = BN * TMAX * U1;                          // 264192
    lse_extract<<<dim3((rows + 3) / 4), dim3(256), 0, stream>>>(
        logits, y, Tl, Ul, blankD, emitD);
    dp_fused<<<dim3(1), dim3(BN * 64), 0, stream>>>(blankD, emitD, Tl, Ul, out);
}

// Round 3
// 752.963 us; speedup vs baseline: 1.1838x; 1.1838x over previous
//
#include <hip/hip_runtime.h>

#define BN   8
#define TMAX 256
#define UMAX 128
#define U1   129   // U_MAX + 1
#define VV   512
#define SD   392   // diagonals allocated; max s read = 391
#define DMAX 384   // fixed DP trip count (max dend = 383)
#define NEG  -1e30f
#define PF   8     // prefetch ring depth (compile-time indexed -> stays in VGPRs)

__device__ __forceinline__ float logaddexpf_(float a, float b) {
    float mx = fmaxf(a, b);
    float d  = fabsf(a - b);
    return mx + __logf(1.0f + __expf(-d));
}

// One wave per (b,t,u) row of 512 logits: LSE + extract blank/emit logp.
// Scratch layout (diagonal-major, interleaved for the DP consumer):
//   cD[b][s][L] : float4 = ( blank[s][2L], blank[s][2L+1],
//                            emitC[s][2L], emitC[s][2L+1] )
//   where emitC[s][u] = emit_logp(t, u-1) with t+(u-1)=s  (consumer-shifted)
//   xD[b][s]    : float2 = ( blank[s][128], emitC[s][128] )
__global__ __launch_bounds__(256) void lse_extract(
        const float* __restrict__ logits,
        const int*   __restrict__ y,
        const int*   __restrict__ Tl,
        const int*   __restrict__ Ul,
        float* __restrict__ cF,
        float* __restrict__ xF) {
    int lane = threadIdx.x & 63;
    int row  = blockIdx.x * 4 + (threadIdx.x >> 6);
    if (row >= BN * TMAX * U1) return;
    int b   = row / (TMAX * U1);
    int rem = row - b * (TMAX * U1);
    int t   = rem / U1;
    int u   = rem - t * U1;
    if (t >= Tl[b] || u > Ul[b]) return;     // never feeds the DP

    const float4* base = (const float4*)(logits + (size_t)row * VV);
    float4 r0 = base[lane * 2];
    float4 r1 = base[lane * 2 + 1];

    float m = fmaxf(fmaxf(fmaxf(r0.x, r0.y), fmaxf(r0.z, r0.w)),
                    fmaxf(fmaxf(r1.x, r1.y), fmaxf(r1.z, r1.w)));
#pragma unroll
    for (int off = 32; off > 0; off >>= 1) m = fmaxf(m, __shfl_xor(m, off));

    float s = __expf(r0.x - m) + __expf(r0.y - m) + __expf(r0.z - m) + __expf(r0.w - m)
            + __expf(r1.x - m) + __expf(r1.y - m) + __expf(r1.z - m) + __expf(r1.w - m);
#pragma unroll
    for (int off = 32; off > 0; off >>= 1) s += __shfl_xor(s, off);

    float lse = m + __logf(s);
    size_t cb = (size_t)b * SD + (t + u);
    if (lane == 0) {
        float bl = r0.x - lse;
        if (u < 128) cF[(cb * 64 + (u >> 1)) * 4 + (u & 1)] = bl;
        else         xF[cb * 2 + 0] = bl;
    }
    if (u < UMAX) {
        int yv = y[b * UMAX + u];            // wave-uniform
        if ((yv >> 3) == lane) {
            int e = yv & 7;
            float v = (e == 0) ? r0.x : (e == 1) ? r0.y : (e == 2) ? r0.z : (e == 3) ? r0.w
                    : (e == 4) ? r1.x : (e == 5) ? r1.y : (e == 6) ? r1.z : r1.w;
            int uc = u + 1;                  // consumer column index
            if (uc < 128) cF[(cb * 64 + (uc >> 1)) * 4 + 2 + (uc & 1)] = v - lse;
            else          xF[cb * 2 + 1] = v - lse;
        }
    }
}

// Barrier-free wavefront DP: one wave per batch (8 waves, 1 block).
// Lane L owns columns u=2L,2L+1; lane 63 also owns u=128.
// Fixed trip count DMAX; masking makes iterations past dend inert; alpha
// captured at d==dend. Ring indices are compile-time constants -> VGPRs.
__global__ __launch_bounds__(512) void dp_fused(
        const float4* __restrict__ cD,
        const float2* __restrict__ xD,
        const int*   __restrict__ Tlp,
        const int*   __restrict__ Ulp,
        float* __restrict__ out) {
    __shared__ float part[BN];
    int w = threadIdx.x >> 6;
    int L = threadIdx.x & 63;
    int Tl = Tlp[w], Ul = Ulp[w];
    int dend = Tl - 1 + Ul;
    const float4* c4 = cD + (size_t)w * SD * 64;
    const float2* x2 = xD + (size_t)w * SD;
    bool lx = (L == 63);
    int  u0 = 2 * L, u1 = 2 * L + 1;
    int  Tm1 = Tl - 1;

    float p0 = (L == 0) ? 0.0f : NEG;        // alpha on diagonal 0
    float p1 = NEG, px = NEG;
    float a0 = NEG, a1 = NEG, ax = NEG;      // captured at d == dend

    float4 ring[PF];
    float2 xr[PF];
#pragma unroll
    for (int i = 0; i < PF; ++i) {
        ring[i] = c4[i * 64 + L];
        xr[i]   = lx ? x2[i] : make_float2(NEG, NEG);
    }

    for (int dc = 1; dc <= DMAX; dc += PF) {
#pragma unroll
        for (int j = 0; j < PF; ++j) {
            int d = dc + j;                  // ring slot = j (compile-time)
            float4 f = ring[j];
            float2 g = xr[j];
            float pm1 = __shfl_up(p1, 1);
            if (L == 0) pm1 = NEG;
            // edges fall out: missing parent is NEG, LAE(NEG,x)==x
            float c0 = logaddexpf_(p0 + f.x, pm1 + f.z);
            float c1 = logaddexpf_(p1 + f.y, p0  + f.w);
            float cx = logaddexpf_(px + g.x, p1  + g.y);
            int ulo = d - Tm1; if (ulo < 0) ulo = 0;
            int uhi = (d < Ul) ? d : Ul;
            p0 = (u0 >= ulo && u0 <= uhi) ? c0 : NEG;
            p1 = (u1 >= ulo && u1 <= uhi) ? c1 : NEG;
            px = (lx && 128 >= ulo && 128 <= uhi) ? cx : NEG;
            if (d == dend) { a0 = p0; a1 = p1; ax = px; }   // wave-uniform branch
            int s = d + PF - 1;              // refill; consumed at d+PF. s<=391<SD
            ring[j] = c4[s * 64 + L];
            xr[j]   = lx ? x2[s] : make_float2(NEG, NEG);
        }
    }

    if (Ul == 128) {
        if (lx) part[w] = ax + x2[dend].x;                  // + blank[Tl-1,128]
    } else if (L == (Ul >> 1)) {
        float af = (Ul & 1) ? a1 : a0;
        const float* cFv = (const float*)c4;
        float bl = cFv[((size_t)dend * 64 + (Ul >> 1)) * 4 + (Ul & 1)];
        part[w] = af + bl;                                  // + blank[Tl-1,Ul]
    }
    __syncthreads();
    if (threadIdx.x == 0) {
        float acc = 0.0f;
#pragma unroll
        for (int i = 0; i < BN; ++i) acc += part[i];
        *out = -acc * (1.0f / BN);
    }
}

extern "C" void kernel_launch(void* const* d_in, const int* in_sizes, int n_in,
                              void* d_out, int out_size, void* d_ws, size_t ws_size,
                              hipStream_t stream) {
    const float* logits = (const float*)d_in[0];
    const int*   y      = (const int*)d_in[1];
    const int*   Tl     = (const int*)d_in[2];
    const int*   Ul     = (const int*)d_in[3];
    float* out = (float*)d_out;

    float* cF = (float*)d_ws;                               // BN*SD*64 float4
    float* xF = cF + (size_t)BN * SD * 64 * 4;              // BN*SD float2

    int rows = BN * TMAX * U1;                              // 264192
    lse_extract<<<dim3((rows + 3) / 4), dim3(256), 0, stream>>>(
        logits, y, Tl, Ul, cF, xF);
    dp_fused<<<dim3(1), dim3(BN * 64), 0, stream>>>(
        (const float4*)cF, (const float2*)xF, Tl, Ul, out);
}